// Round 5
// baseline (706.682 us; speedup 1.0000x reference)
//
#include <hip/hip_runtime.h>

#define NODES 50000
#define RELS  3
#define NEDGE 600000
#define FIN   128
#define FHID  64
#define FOUT  64
#define SEGS  (RELS * NODES)            // 150000 (rel, dst) segments
#define NBLK  ((SEGS + 255) / 256)      // 586 scan blocks

// ---------------- degree counting (int) ----------------
__global__ __launch_bounds__(256) void deg_kernel(const int* __restrict__ src,
                                                  const int* __restrict__ dst,
                                                  int* __restrict__ odI,
                                                  int* __restrict__ idI) {
    int e = blockIdx.x * 256 + threadIdx.x;
    int r = blockIdx.y;
    if (e >= NEDGE) return;
    atomicAdd(&odI[r * NODES + src[r * NEDGE + e]], 1);
    atomicAdd(&idI[r * NODES + dst[r * NEDGE + e]], 1);
}

// ---------------- norms from int degrees ----------------
__global__ __launch_bounds__(256) void norm_kernel(const int* __restrict__ odI,
                                                   const int* __restrict__ idI,
                                                   float* __restrict__ outnorm,
                                                   float* __restrict__ innorm) {
    int i = blockIdx.x * 256 + threadIdx.x;
    if (i >= SEGS) return;
    outnorm[i] = 1.0f / sqrtf(fmaxf((float)odI[i], 1.0f));
    innorm[i]  = 1.0f / sqrtf(fmaxf((float)idI[i], 1.0f));
}

// ---------------- exclusive scan over idI (3 kernels) ----------------
__global__ __launch_bounds__(256) void scan_sums_kernel(const int* __restrict__ idI,
                                                        int* __restrict__ partials) {
    __shared__ int s[256];
    int i = blockIdx.x * 256 + threadIdx.x;
    s[threadIdx.x] = (i < SEGS) ? idI[i] : 0;
    __syncthreads();
    for (int off = 128; off > 0; off >>= 1) {
        if (threadIdx.x < off) s[threadIdx.x] += s[threadIdx.x + off];
        __syncthreads();
    }
    if (threadIdx.x == 0) partials[blockIdx.x] = s[0];
}

__global__ __launch_bounds__(1024) void scan_partials_kernel(int* __restrict__ partials) {
    __shared__ int s[1024];
    int tid = threadIdx.x;
    int v = (tid < NBLK) ? partials[tid] : 0;
    s[tid] = v;
    __syncthreads();
    for (int off = 1; off < 1024; off <<= 1) {
        int t = s[tid];
        int add = (tid >= off) ? s[tid - off] : 0;
        __syncthreads();
        s[tid] = t + add;
        __syncthreads();
    }
    if (tid < NBLK) partials[tid] = s[tid] - v;   // exclusive
}

__global__ __launch_bounds__(256) void scan_write_kernel(const int* __restrict__ idI,
                                                         const int* __restrict__ partials,
                                                         int* __restrict__ offs) {
    __shared__ int s[256];
    int tid = threadIdx.x;
    int i = blockIdx.x * 256 + tid;
    int v = (i < SEGS) ? idI[i] : 0;
    s[tid] = v;
    __syncthreads();
    for (int off = 1; off < 256; off <<= 1) {
        int t = s[tid];
        int add = (tid >= off) ? s[tid - off] : 0;
        __syncthreads();
        s[tid] = t + add;
        __syncthreads();
    }
    if (i < SEGS) offs[i] = partials[blockIdx.x] + (s[tid] - v);
}

// ---------------- CSR fill: bucket src ids by (rel,dst) ----------------
__global__ __launch_bounds__(256) void fill_kernel(const int* __restrict__ src,
                                                   const int* __restrict__ dst,
                                                   const int* __restrict__ offs,
                                                   int* __restrict__ cursor,
                                                   int* __restrict__ edge_src) {
    int e = blockIdx.x * 256 + threadIdx.x;
    int r = blockIdx.y;
    if (e >= NEDGE) return;
    int seg = r * NODES + dst[r * NEDGE + e];
    int pos = offs[seg] + atomicAdd(&cursor[seg], 1);
    edge_src[pos] = src[r * NEDGE + e];
}

// ---------------- layer 1 GEMM: h[r][n][j] = (x[n,:].W1[r][:,j]) * outnorm[r][n]
// 8 rows/thread, no LDS (W direct from global, L1-resident), explicit ping-pong
// double-buffer so 12 independent loads are in flight during every FMA block.
// __launch_bounds__(256,4): VGPR<=128 so both buffers stay resident, 4 blk/CU.
__global__ __launch_bounds__(256, 4) void gemm1_kernel(const float* __restrict__ x,
                                                       const float* __restrict__ W1,
                                                       const float* __restrict__ outnorm,
                                                       float* __restrict__ h) {
    int r  = blockIdx.y;
    int j  = threadIdx.x & 63;
    int wv = threadIdx.x >> 6;
    int n0 = (blockIdx.x * 4 + wv) * 8;
    if (n0 + 8 > NODES) n0 = NODES - 8;       // tail waves redo rows (same values)
    const float* xb = x + (size_t)n0 * FIN;
    const float* Wc = W1 + (size_t)r * FIN * FHID + j;

    float acc[8];
#pragma unroll
    for (int i = 0; i < 8; ++i) acc[i] = 0.f;

    float4 A0[8], A1[8], Wv0, Wv1;
    auto loadx = [&](float4* buf, int k4) {
        const float* p = xb + k4 * 4;
#pragma unroll
        for (int i = 0; i < 8; ++i) buf[i] = *(const float4*)(p + (size_t)i * FIN);
    };
    auto loadw = [&](float4& w4, int k4) {
        const float* p = Wc + (size_t)k4 * 4 * FHID;
        w4.x = p[0]; w4.y = p[FHID]; w4.z = p[2 * FHID]; w4.w = p[3 * FHID];
    };
    auto fmas = [&](const float4* a, const float4& w4) {
#pragma unroll
        for (int i = 0; i < 8; ++i) {
            acc[i] = fmaf(a[i].x, w4.x, acc[i]);
            acc[i] = fmaf(a[i].y, w4.y, acc[i]);
            acc[i] = fmaf(a[i].z, w4.z, acc[i]);
            acc[i] = fmaf(a[i].w, w4.w, acc[i]);
        }
    };

    loadx(A0, 0); loadw(Wv0, 0);
#pragma unroll 1
    for (int k4 = 0; k4 < FIN / 4; k4 += 2) {
        loadx(A1, k4 + 1); loadw(Wv1, k4 + 1);
        fmas(A0, Wv0);
        int kn = (k4 + 2 < FIN / 4) ? (k4 + 2) : 0;   // clamped dummy prefetch on last iter
        loadx(A0, kn); loadw(Wv0, kn);
        fmas(A1, Wv1);
    }

    const float* on = outnorm + r * NODES + n0;
    float* hb = h + ((size_t)r * NODES + n0) * FHID + j;
#pragma unroll
    for (int i = 0; i < 8; ++i) hb[(size_t)i * FHID] = acc[i] * on[i];
}

// ---------------- layer 1 gather ----------------
// One wave per dst node; lanes = 4 edges x 16 float4-slots. 1 KB gathered/instr.
__global__ __launch_bounds__(256) void gather1_kernel(const float* __restrict__ h,
                                                      const int* __restrict__ es,
                                                      const int* __restrict__ offs,
                                                      const int* __restrict__ cnt,
                                                      const float* __restrict__ innorm,
                                                      const float* __restrict__ b1,
                                                      float* __restrict__ B) {
    int lane = threadIdx.x & 63;
    int wv   = threadIdx.x >> 6;
    int d    = blockIdx.x * 4 + wv;           // NODES % 4 == 0
    int q    = lane & 15;                     // float4 slot within row
    int e4   = lane >> 4;                     // which of 4 edges
    float4 tot = {0.f, 0.f, 0.f, 0.f};
#pragma unroll
    for (int r = 0; r < RELS; ++r) {
        int seg = r * NODES + d;
        int o = offs[seg], c = cnt[seg];
        const float* Ar = h + (size_t)r * NODES * FHID;
        float4 s = {0.f, 0.f, 0.f, 0.f};
        int t = 0;
#pragma unroll 2
        for (; t + 4 <= c; t += 4) {
            int idx = es[o + t + e4];
            float4 v = *(const float4*)(Ar + (size_t)idx * FHID + q * 4);
            s.x += v.x; s.y += v.y; s.z += v.z; s.w += v.w;
        }
        int rem = c - t;
        if (e4 < rem) {
            int idx = es[o + t + e4];
            float4 v = *(const float4*)(Ar + (size_t)idx * FHID + q * 4);
            s.x += v.x; s.y += v.y; s.z += v.z; s.w += v.w;
        }
        float inr = innorm[seg];
        tot.x = fmaf(inr, s.x, tot.x); tot.y = fmaf(inr, s.y, tot.y);
        tot.z = fmaf(inr, s.z, tot.z); tot.w = fmaf(inr, s.w, tot.w);
    }
    // reduce across the 4 edge groups (lanes differing in bits 4,5)
    tot.x += __shfl_xor(tot.x, 16); tot.y += __shfl_xor(tot.y, 16);
    tot.z += __shfl_xor(tot.z, 16); tot.w += __shfl_xor(tot.w, 16);
    tot.x += __shfl_xor(tot.x, 32); tot.y += __shfl_xor(tot.y, 32);
    tot.z += __shfl_xor(tot.z, 32); tot.w += __shfl_xor(tot.w, 32);
    if (lane < 16) {
        float4 bs0 = ((const float4*)b1)[q];
        float4 bs1 = ((const float4*)(b1 + FHID))[q];
        float4 bs2 = ((const float4*)(b1 + 2 * FHID))[q];
        float4 o4;
        o4.x = fmaxf(tot.x + bs0.x + bs1.x + bs2.x, 0.f);
        o4.y = fmaxf(tot.y + bs0.y + bs1.y + bs2.y, 0.f);
        o4.z = fmaxf(tot.z + bs0.z + bs1.z + bs2.z, 0.f);
        o4.w = fmaxf(tot.w + bs0.w + bs1.w + bs2.w, 0.f);
        *(float4*)(B + (size_t)d * FHID + q * 4) = o4;
    }
}

// ---------------- layer 2 gather: A[r][d][j] = innorm[r][d]*sum_e outnorm[r][src]*h1[src][j]
__global__ __launch_bounds__(256) void gather2_kernel(const float* __restrict__ h1,
                                                      const int* __restrict__ es,
                                                      const int* __restrict__ offs,
                                                      const int* __restrict__ cnt,
                                                      const float* __restrict__ outnorm,
                                                      const float* __restrict__ innorm,
                                                      float* __restrict__ A) {
    int lane = threadIdx.x & 63;
    int wv   = threadIdx.x >> 6;
    int d    = blockIdx.x * 4 + wv;
    int r    = blockIdx.y;
    int q    = lane & 15;
    int e4   = lane >> 4;
    int seg = r * NODES + d;
    int o = offs[seg], c = cnt[seg];
    const float* on = outnorm + r * NODES;
    float4 s = {0.f, 0.f, 0.f, 0.f};
    int t = 0;
#pragma unroll 2
    for (; t + 4 <= c; t += 4) {
        int idx = es[o + t + e4];
        float w = on[idx];
        float4 v = *(const float4*)(h1 + (size_t)idx * FHID + q * 4);
        s.x = fmaf(w, v.x, s.x); s.y = fmaf(w, v.y, s.y);
        s.z = fmaf(w, v.z, s.z); s.w = fmaf(w, v.w, s.w);
    }
    int rem = c - t;
    if (e4 < rem) {
        int idx = es[o + t + e4];
        float w = on[idx];
        float4 v = *(const float4*)(h1 + (size_t)idx * FHID + q * 4);
        s.x = fmaf(w, v.x, s.x); s.y = fmaf(w, v.y, s.y);
        s.z = fmaf(w, v.z, s.z); s.w = fmaf(w, v.w, s.w);
    }
    s.x += __shfl_xor(s.x, 16); s.y += __shfl_xor(s.y, 16);
    s.z += __shfl_xor(s.z, 16); s.w += __shfl_xor(s.w, 16);
    s.x += __shfl_xor(s.x, 32); s.y += __shfl_xor(s.y, 32);
    s.z += __shfl_xor(s.z, 32); s.w += __shfl_xor(s.w, 32);
    if (lane < 16) {
        float inr = innorm[seg];
        float4 o4 = {inr * s.x, inr * s.y, inr * s.z, inr * s.w};
        *(float4*)(A + (size_t)seg * FHID + q * 4) = o4;
    }
}

// ---------------- layer 2 GEMM + combine: out = sum_r A[r] @ W2[r] + sum_r b2[r]
// Same no-LDS ping-pong structure; K flattened over (rel, k4) = 48 steps.
__global__ __launch_bounds__(256, 4) void out_kernel(const float* __restrict__ agg2,
                                                     const float* __restrict__ W2,
                                                     const float* __restrict__ b2,
                                                     float* __restrict__ out) {
    int j  = threadIdx.x & 63;
    int wv = threadIdx.x >> 6;
    int n0 = (blockIdx.x * 4 + wv) * 8;
    if (n0 + 8 > NODES) n0 = NODES - 8;
    float bsum = b2[j] + b2[FOUT + j] + b2[2 * FOUT + j];
    float acc[8];
#pragma unroll
    for (int i = 0; i < 8; ++i) acc[i] = bsum;

    float4 A0[8], A1[8], Wv0, Wv1;
    auto loada = [&](float4* buf, int kk) {
        int r = kk >> 4, k4 = kk & 15;
        const float* p = agg2 + ((size_t)r * NODES + n0) * FHID + k4 * 4;
#pragma unroll
        for (int i = 0; i < 8; ++i) buf[i] = *(const float4*)(p + (size_t)i * FHID);
    };
    auto loadw = [&](float4& w4, int kk) {
        int r = kk >> 4, k4 = kk & 15;
        const float* p = W2 + (size_t)r * FHID * FOUT + (size_t)k4 * 4 * FOUT + j;
        w4.x = p[0]; w4.y = p[FOUT]; w4.z = p[2 * FOUT]; w4.w = p[3 * FOUT];
    };
    auto fmas = [&](const float4* a, const float4& w4) {
#pragma unroll
        for (int i = 0; i < 8; ++i) {
            acc[i] = fmaf(a[i].x, w4.x, acc[i]);
            acc[i] = fmaf(a[i].y, w4.y, acc[i]);
            acc[i] = fmaf(a[i].z, w4.z, acc[i]);
            acc[i] = fmaf(a[i].w, w4.w, acc[i]);
        }
    };

    loada(A0, 0); loadw(Wv0, 0);
#pragma unroll 1
    for (int kk = 0; kk < RELS * FHID / 4; kk += 2) {   // 48 steps
        loada(A1, kk + 1); loadw(Wv1, kk + 1);
        fmas(A0, Wv0);
        int kn = (kk + 2 < RELS * FHID / 4) ? (kk + 2) : 0;
        loada(A0, kn); loadw(Wv0, kn);
        fmas(A1, Wv1);
    }

    float* ob = out + (size_t)n0 * FOUT + j;
#pragma unroll
    for (int i = 0; i < 8; ++i) ob[(size_t)i * FOUT] = acc[i];
}

extern "C" void kernel_launch(void* const* d_in, const int* in_sizes, int n_in,
                              void* d_out, int out_size, void* d_ws, size_t ws_size,
                              hipStream_t stream) {
    const float* x   = (const float*)d_in[0];   // [N,128]
    const float* W1  = (const float*)d_in[1];   // [3,128,64]
    const float* b1  = (const float*)d_in[2];   // [3,64]
    const float* W2  = (const float*)d_in[3];   // [3,64,64]
    const float* b2  = (const float*)d_in[4];   // [3,64]
    const int*   src = (const int*)d_in[5];     // [3,E]
    const int*   dst = (const int*)d_in[6];     // [3,E]
    float* out = (float*)d_out;                 // [N,64]

    // workspace layout: odI | idI | cursor | offs | partials(1024) | edge_src | outnorm | innorm | A | B
    int*   odI      = (int*)d_ws;
    int*   idI      = odI + SEGS;
    int*   cursor   = idI + SEGS;
    int*   offs     = cursor + SEGS;
    int*   partials = offs + SEGS;
    int*   edge_src = partials + 1024;
    float* outnorm  = (float*)(edge_src + (size_t)RELS * NEDGE);
    float* innorm   = outnorm + SEGS;
    float* A        = innorm + SEGS;                  // [3,N,64] layer-1 h / layer-2 agg
    float* B        = A + (size_t)SEGS * FHID;        // [N,64]   layer-1 output (h1)

    const int EB = (NEDGE + 255) / 256;               // 2344
    const int GB = (NODES / 8 + 3) / 4;               // 1563 blocks of 4 waves x 8 rows

    // zero odI, idI, cursor (contiguous)
    hipMemsetAsync(odI, 0, 3ull * SEGS * sizeof(int), stream);

    // degrees + norms (shared by both layers)
    deg_kernel<<<dim3(EB, RELS), 256, 0, stream>>>(src, dst, odI, idI);
    norm_kernel<<<(SEGS + 255) / 256, 256, 0, stream>>>(odI, idI, outnorm, innorm);

    // CSR build on dst (shared by both layers)
    scan_sums_kernel<<<NBLK, 256, 0, stream>>>(idI, partials);
    scan_partials_kernel<<<1, 1024, 0, stream>>>(partials);
    scan_write_kernel<<<NBLK, 256, 0, stream>>>(idI, partials, offs);
    fill_kernel<<<dim3(EB, RELS), 256, 0, stream>>>(src, dst, offs, cursor, edge_src);

    // layer 1
    gemm1_kernel<<<dim3(GB, RELS), 256, 0, stream>>>(x, W1, outnorm, A);
    gather1_kernel<<<NODES / 4, 256, 0, stream>>>(A, edge_src, offs, idI, innorm, b1, B);

    // layer 2
    gather2_kernel<<<dim3(NODES / 4, RELS), 256, 0, stream>>>(B, edge_src, offs, idI, outnorm, innorm, A);
    out_kernel<<<GB, 256, 0, stream>>>(A, W2, b2, out);
}

// Round 6
// 627.322 us; speedup vs baseline: 1.1265x; 1.1265x over previous
//
#include <hip/hip_runtime.h>

#define NODES 50000
#define RELS  3
#define NEDGE 600000
#define FIN   128
#define FHID  64
#define FOUT  64
#define SEGS  (RELS * NODES)            // 150000 (rel, dst) segments
#define NBLK  ((SEGS + 255) / 256)      // 586 scan blocks

// ---------------- degree counting (int) ----------------
__global__ __launch_bounds__(256) void deg_kernel(const int* __restrict__ src,
                                                  const int* __restrict__ dst,
                                                  int* __restrict__ odI,
                                                  int* __restrict__ idI) {
    int e = blockIdx.x * 256 + threadIdx.x;
    int r = blockIdx.y;
    if (e >= NEDGE) return;
    atomicAdd(&odI[r * NODES + src[r * NEDGE + e]], 1);
    atomicAdd(&idI[r * NODES + dst[r * NEDGE + e]], 1);
}

// ---------------- norms from int degrees ----------------
__global__ __launch_bounds__(256) void norm_kernel(const int* __restrict__ odI,
                                                   const int* __restrict__ idI,
                                                   float* __restrict__ outnorm,
                                                   float* __restrict__ innorm) {
    int i = blockIdx.x * 256 + threadIdx.x;
    if (i >= SEGS) return;
    outnorm[i] = 1.0f / sqrtf(fmaxf((float)odI[i], 1.0f));
    innorm[i]  = 1.0f / sqrtf(fmaxf((float)idI[i], 1.0f));
}

// ---------------- exclusive scan over idI (3 kernels) ----------------
__global__ __launch_bounds__(256) void scan_sums_kernel(const int* __restrict__ idI,
                                                        int* __restrict__ partials) {
    __shared__ int s[256];
    int i = blockIdx.x * 256 + threadIdx.x;
    s[threadIdx.x] = (i < SEGS) ? idI[i] : 0;
    __syncthreads();
    for (int off = 128; off > 0; off >>= 1) {
        if (threadIdx.x < off) s[threadIdx.x] += s[threadIdx.x + off];
        __syncthreads();
    }
    if (threadIdx.x == 0) partials[blockIdx.x] = s[0];
}

__global__ __launch_bounds__(1024) void scan_partials_kernel(int* __restrict__ partials) {
    __shared__ int s[1024];
    int tid = threadIdx.x;
    int v = (tid < NBLK) ? partials[tid] : 0;
    s[tid] = v;
    __syncthreads();
    for (int off = 1; off < 1024; off <<= 1) {
        int t = s[tid];
        int add = (tid >= off) ? s[tid - off] : 0;
        __syncthreads();
        s[tid] = t + add;
        __syncthreads();
    }
    if (tid < NBLK) partials[tid] = s[tid] - v;   // exclusive
}

__global__ __launch_bounds__(256) void scan_write_kernel(const int* __restrict__ idI,
                                                         const int* __restrict__ partials,
                                                         int* __restrict__ offs) {
    __shared__ int s[256];
    int tid = threadIdx.x;
    int i = blockIdx.x * 256 + tid;
    int v = (i < SEGS) ? idI[i] : 0;
    s[tid] = v;
    __syncthreads();
    for (int off = 1; off < 256; off <<= 1) {
        int t = s[tid];
        int add = (tid >= off) ? s[tid - off] : 0;
        __syncthreads();
        s[tid] = t + add;
        __syncthreads();
    }
    if (i < SEGS) offs[i] = partials[blockIdx.x] + (s[tid] - v);
}

// ---------------- CSR fill: bucket src ids by (rel,dst) ----------------
__global__ __launch_bounds__(256) void fill_kernel(const int* __restrict__ src,
                                                   const int* __restrict__ dst,
                                                   const int* __restrict__ offs,
                                                   int* __restrict__ cursor,
                                                   int* __restrict__ edge_src) {
    int e = blockIdx.x * 256 + threadIdx.x;
    int r = blockIdx.y;
    if (e >= NEDGE) return;
    int seg = r * NODES + dst[r * NEDGE + e];
    int pos = offs[seg] + atomicAdd(&cursor[seg], 1);
    edge_src[pos] = src[r * NEDGE + e];
}

// ---------------- layer 1 GEMM, ALL relations in one pass ----------------
// h[r][n][j] = (x[n,:].W1[r][:,j]) * outnorm[r][n]
// Wave = 8 nodes x 64 cols x 3 relations: the 8 x-float4 loads per k4 are
// shared across all 3 relations (96 FMAs per 20 load instrs; x fetched ONCE).
__global__ __launch_bounds__(256, 4) void gemm1_kernel(const float* __restrict__ x,
                                                       const float* __restrict__ W1,
                                                       const float* __restrict__ outnorm,
                                                       float* __restrict__ h) {
    int j  = threadIdx.x & 63;
    int wv = threadIdx.x >> 6;
    int n0 = (blockIdx.x * 4 + wv) * 8;
    if (n0 + 8 > NODES) n0 = NODES - 8;       // tail waves redo rows (same values)
    const float* xb = x + (size_t)n0 * FIN;

    float acc[RELS][8];
#pragma unroll
    for (int r = 0; r < RELS; ++r)
#pragma unroll
        for (int i = 0; i < 8; ++i) acc[r][i] = 0.f;

#pragma unroll 1
    for (int k4 = 0; k4 < FIN / 4; ++k4) {
        float4 a[8];
#pragma unroll
        for (int i = 0; i < 8; ++i)
            a[i] = *(const float4*)(xb + (size_t)i * FIN + k4 * 4);
#pragma unroll
        for (int r = 0; r < RELS; ++r) {
            const float* wp = W1 + (size_t)r * FIN * FHID + (size_t)k4 * 4 * FHID + j;
            float w0 = wp[0], w1 = wp[FHID], w2 = wp[2 * FHID], w3 = wp[3 * FHID];
#pragma unroll
            for (int i = 0; i < 8; ++i) {
                acc[r][i] = fmaf(a[i].x, w0, acc[r][i]);
                acc[r][i] = fmaf(a[i].y, w1, acc[r][i]);
                acc[r][i] = fmaf(a[i].z, w2, acc[r][i]);
                acc[r][i] = fmaf(a[i].w, w3, acc[r][i]);
            }
        }
    }

#pragma unroll
    for (int r = 0; r < RELS; ++r) {
        const float* on = outnorm + r * NODES + n0;
        float* hb = h + ((size_t)r * NODES + n0) * FHID + j;
#pragma unroll
        for (int i = 0; i < 8; ++i) hb[(size_t)i * FHID] = acc[r][i] * on[i];
    }
}

// ---------------- layer 1 gather ----------------
// One wave per dst node; lanes = 4 edges x 16 float4-slots; manual 8-edge
// batching with dual accumulators -> 2 independent gathers in flight per lane.
__global__ __launch_bounds__(256) void gather1_kernel(const float* __restrict__ h,
                                                      const int* __restrict__ es,
                                                      const int* __restrict__ offs,
                                                      const int* __restrict__ cnt,
                                                      const float* __restrict__ innorm,
                                                      const float* __restrict__ b1,
                                                      float* __restrict__ B) {
    int lane = threadIdx.x & 63;
    int wv   = threadIdx.x >> 6;
    int d    = blockIdx.x * 4 + wv;           // NODES % 4 == 0
    int q    = lane & 15;                     // float4 slot within row
    int e4   = lane >> 4;                     // which of 4 edges
    float4 tot = {0.f, 0.f, 0.f, 0.f};
#pragma unroll
    for (int r = 0; r < RELS; ++r) {
        int seg = r * NODES + d;
        int o = offs[seg], c = cnt[seg];
        const float* Ar = h + (size_t)r * NODES * FHID;
        float4 s0 = {0.f, 0.f, 0.f, 0.f}, s1 = {0.f, 0.f, 0.f, 0.f};
        int t = 0;
        for (; t + 8 <= c; t += 8) {
            int ia = es[o + t + e4];
            int ib = es[o + t + 4 + e4];
            float4 va = *(const float4*)(Ar + (size_t)ia * FHID + q * 4);
            float4 vb = *(const float4*)(Ar + (size_t)ib * FHID + q * 4);
            s0.x += va.x; s0.y += va.y; s0.z += va.z; s0.w += va.w;
            s1.x += vb.x; s1.y += vb.y; s1.z += vb.z; s1.w += vb.w;
        }
        if (t + 4 <= c) {
            int ia = es[o + t + e4];
            float4 va = *(const float4*)(Ar + (size_t)ia * FHID + q * 4);
            s0.x += va.x; s0.y += va.y; s0.z += va.z; s0.w += va.w;
            t += 4;
        }
        int rem = c - t;
        if (e4 < rem) {
            int ia = es[o + t + e4];
            float4 va = *(const float4*)(Ar + (size_t)ia * FHID + q * 4);
            s1.x += va.x; s1.y += va.y; s1.z += va.z; s1.w += va.w;
        }
        float inr = innorm[seg];
        tot.x = fmaf(inr, s0.x + s1.x, tot.x);
        tot.y = fmaf(inr, s0.y + s1.y, tot.y);
        tot.z = fmaf(inr, s0.z + s1.z, tot.z);
        tot.w = fmaf(inr, s0.w + s1.w, tot.w);
    }
    // reduce across the 4 edge groups (lanes differing in bits 4,5)
    tot.x += __shfl_xor(tot.x, 16); tot.y += __shfl_xor(tot.y, 16);
    tot.z += __shfl_xor(tot.z, 16); tot.w += __shfl_xor(tot.w, 16);
    tot.x += __shfl_xor(tot.x, 32); tot.y += __shfl_xor(tot.y, 32);
    tot.z += __shfl_xor(tot.z, 32); tot.w += __shfl_xor(tot.w, 32);
    if (lane < 16) {
        float4 bs0 = ((const float4*)b1)[q];
        float4 bs1 = ((const float4*)(b1 + FHID))[q];
        float4 bs2 = ((const float4*)(b1 + 2 * FHID))[q];
        float4 o4;
        o4.x = fmaxf(tot.x + bs0.x + bs1.x + bs2.x, 0.f);
        o4.y = fmaxf(tot.y + bs0.y + bs1.y + bs2.y, 0.f);
        o4.z = fmaxf(tot.z + bs0.z + bs1.z + bs2.z, 0.f);
        o4.w = fmaxf(tot.w + bs0.w + bs1.w + bs2.w, 0.f);
        *(float4*)(B + (size_t)d * FHID + q * 4) = o4;
    }
}

// ---------------- layer 2 gather: A[r][d][j] = innorm[r][d]*sum_e outnorm[r][src]*h1[src][j]
__global__ __launch_bounds__(256) void gather2_kernel(const float* __restrict__ h1,
                                                      const int* __restrict__ es,
                                                      const int* __restrict__ offs,
                                                      const int* __restrict__ cnt,
                                                      const float* __restrict__ outnorm,
                                                      const float* __restrict__ innorm,
                                                      float* __restrict__ A) {
    int lane = threadIdx.x & 63;
    int wv   = threadIdx.x >> 6;
    int d    = blockIdx.x * 4 + wv;
    int r    = blockIdx.y;
    int q    = lane & 15;
    int e4   = lane >> 4;
    int seg = r * NODES + d;
    int o = offs[seg], c = cnt[seg];
    const float* on = outnorm + r * NODES;
    float4 s0 = {0.f, 0.f, 0.f, 0.f}, s1 = {0.f, 0.f, 0.f, 0.f};
    int t = 0;
    for (; t + 8 <= c; t += 8) {
        int ia = es[o + t + e4];
        int ib = es[o + t + 4 + e4];
        float wa = on[ia], wb = on[ib];
        float4 va = *(const float4*)(h1 + (size_t)ia * FHID + q * 4);
        float4 vb = *(const float4*)(h1 + (size_t)ib * FHID + q * 4);
        s0.x = fmaf(wa, va.x, s0.x); s0.y = fmaf(wa, va.y, s0.y);
        s0.z = fmaf(wa, va.z, s0.z); s0.w = fmaf(wa, va.w, s0.w);
        s1.x = fmaf(wb, vb.x, s1.x); s1.y = fmaf(wb, vb.y, s1.y);
        s1.z = fmaf(wb, vb.z, s1.z); s1.w = fmaf(wb, vb.w, s1.w);
    }
    if (t + 4 <= c) {
        int ia = es[o + t + e4];
        float wa = on[ia];
        float4 va = *(const float4*)(h1 + (size_t)ia * FHID + q * 4);
        s0.x = fmaf(wa, va.x, s0.x); s0.y = fmaf(wa, va.y, s0.y);
        s0.z = fmaf(wa, va.z, s0.z); s0.w = fmaf(wa, va.w, s0.w);
        t += 4;
    }
    int rem = c - t;
    if (e4 < rem) {
        int ia = es[o + t + e4];
        float wa = on[ia];
        float4 va = *(const float4*)(h1 + (size_t)ia * FHID + q * 4);
        s1.x = fmaf(wa, va.x, s1.x); s1.y = fmaf(wa, va.y, s1.y);
        s1.z = fmaf(wa, va.z, s1.z); s1.w = fmaf(wa, va.w, s1.w);
    }
    float4 s = {s0.x + s1.x, s0.y + s1.y, s0.z + s1.z, s0.w + s1.w};
    s.x += __shfl_xor(s.x, 16); s.y += __shfl_xor(s.y, 16);
    s.z += __shfl_xor(s.z, 16); s.w += __shfl_xor(s.w, 16);
    s.x += __shfl_xor(s.x, 32); s.y += __shfl_xor(s.y, 32);
    s.z += __shfl_xor(s.z, 32); s.w += __shfl_xor(s.w, 32);
    if (lane < 16) {
        float inr = innorm[seg];
        float4 o4 = {inr * s.x, inr * s.y, inr * s.z, inr * s.w};
        *(float4*)(A + (size_t)seg * FHID + q * 4) = o4;
    }
}

// ---------------- layer 2 GEMM + combine: out = sum_r A[r] @ W2[r] + sum_r b2[r]
// Straight 48-step K loop; 8 independent A loads + 4 W loads per step.
__global__ __launch_bounds__(256, 4) void out_kernel(const float* __restrict__ agg2,
                                                     const float* __restrict__ W2,
                                                     const float* __restrict__ b2,
                                                     float* __restrict__ out) {
    int j  = threadIdx.x & 63;
    int wv = threadIdx.x >> 6;
    int n0 = (blockIdx.x * 4 + wv) * 8;
    if (n0 + 8 > NODES) n0 = NODES - 8;
    float bsum = b2[j] + b2[FOUT + j] + b2[2 * FOUT + j];
    float acc[8];
#pragma unroll
    for (int i = 0; i < 8; ++i) acc[i] = bsum;

#pragma unroll 1
    for (int kk = 0; kk < RELS * FHID / 4; ++kk) {   // 48 steps
        int r = kk >> 4, k4 = kk & 15;
        const float* ap = agg2 + ((size_t)r * NODES + n0) * FHID + k4 * 4;
        float4 a[8];
#pragma unroll
        for (int i = 0; i < 8; ++i) a[i] = *(const float4*)(ap + (size_t)i * FHID);
        const float* wp = W2 + (size_t)r * FHID * FOUT + (size_t)k4 * 4 * FOUT + j;
        float w0 = wp[0], w1 = wp[FOUT], w2 = wp[2 * FOUT], w3 = wp[3 * FOUT];
#pragma unroll
        for (int i = 0; i < 8; ++i) {
            acc[i] = fmaf(a[i].x, w0, acc[i]);
            acc[i] = fmaf(a[i].y, w1, acc[i]);
            acc[i] = fmaf(a[i].z, w2, acc[i]);
            acc[i] = fmaf(a[i].w, w3, acc[i]);
        }
    }

    float* ob = out + (size_t)n0 * FOUT + j;
#pragma unroll
    for (int i = 0; i < 8; ++i) ob[(size_t)i * FOUT] = acc[i];
}

extern "C" void kernel_launch(void* const* d_in, const int* in_sizes, int n_in,
                              void* d_out, int out_size, void* d_ws, size_t ws_size,
                              hipStream_t stream) {
    const float* x   = (const float*)d_in[0];   // [N,128]
    const float* W1  = (const float*)d_in[1];   // [3,128,64]
    const float* b1  = (const float*)d_in[2];   // [3,64]
    const float* W2  = (const float*)d_in[3];   // [3,64,64]
    const float* b2  = (const float*)d_in[4];   // [3,64]
    const int*   src = (const int*)d_in[5];     // [3,E]
    const int*   dst = (const int*)d_in[6];     // [3,E]
    float* out = (float*)d_out;                 // [N,64]

    // workspace layout: odI | idI | cursor | offs | partials(1024) | edge_src | outnorm | innorm | A | B
    int*   odI      = (int*)d_ws;
    int*   idI      = odI + SEGS;
    int*   cursor   = idI + SEGS;
    int*   offs     = cursor + SEGS;
    int*   partials = offs + SEGS;
    int*   edge_src = partials + 1024;
    float* outnorm  = (float*)(edge_src + (size_t)RELS * NEDGE);
    float* innorm   = outnorm + SEGS;
    float* A        = innorm + SEGS;                  // [3,N,64] layer-1 h / layer-2 agg
    float* B        = A + (size_t)SEGS * FHID;        // [N,64]   layer-1 output (h1)

    const int EB = (NEDGE + 255) / 256;               // 2344
    const int GB = (NODES / 8 + 3) / 4;               // 1563 blocks of 4 waves x 8 rows

    // zero odI, idI, cursor (contiguous)
    hipMemsetAsync(odI, 0, 3ull * SEGS * sizeof(int), stream);

    // degrees + norms (shared by both layers)
    deg_kernel<<<dim3(EB, RELS), 256, 0, stream>>>(src, dst, odI, idI);
    norm_kernel<<<(SEGS + 255) / 256, 256, 0, stream>>>(odI, idI, outnorm, innorm);

    // CSR build on dst (shared by both layers)
    scan_sums_kernel<<<NBLK, 256, 0, stream>>>(idI, partials);
    scan_partials_kernel<<<1, 1024, 0, stream>>>(partials);
    scan_write_kernel<<<NBLK, 256, 0, stream>>>(idI, partials, offs);
    fill_kernel<<<dim3(EB, RELS), 256, 0, stream>>>(src, dst, offs, cursor, edge_src);

    // layer 1 (gemm over ALL relations in one pass)
    gemm1_kernel<<<GB, 256, 0, stream>>>(x, W1, outnorm, A);
    gather1_kernel<<<NODES / 4, 256, 0, stream>>>(A, edge_src, offs, idI, innorm, b1, B);

    // layer 2
    gather2_kernel<<<dim3(NODES / 4, RELS), 256, 0, stream>>>(B, edge_src, offs, idI, outnorm, innorm, A);
    out_kernel<<<GB, 256, 0, stream>>>(A, W2, b2, out);
}

// Round 7
// 487.483 us; speedup vs baseline: 1.4497x; 1.2869x over previous
//
#include <hip/hip_runtime.h>

#define NODES 50000
#define RELS  3
#define NEDGE 600000
#define FIN   128
#define FHID  64
#define FOUT  64
#define SEGS  (RELS * NODES)            // 150000 (rel, dst) segments
#define NBLK  ((SEGS + 255) / 256)      // 586 scan blocks

#define HC     32                       // histogram chunks per edge array
#define HCHUNK (NEDGE / HC)             // 18750 (exact)
#define HWORDS 16384                    // 32768 u16 bins packed in u32 words (64 KB LDS)

// ---------------- LDS-staged histogram: no global atomics ----------------
// grid = (chunk, job, range); job 0..2 = src[r] (out-deg), 3..5 = dst[r] (in-deg)
// range rg covers nodes [rg*32768, ...): membership test is (v>>15)==rg.
__global__ __launch_bounds__(256) void hist_kernel(const int* __restrict__ src,
                                                   const int* __restrict__ dst,
                                                   unsigned int* __restrict__ slab32) {
    __shared__ unsigned int bins[HWORDS];          // 64 KB, u16-packed counts
    int chunk = blockIdx.x, job = blockIdx.y, rg = blockIdx.z;
    const int* arr = (job < 3 ? src + (size_t)job * NEDGE
                              : dst + (size_t)(job - 3) * NEDGE) + (size_t)chunk * HCHUNK;
    for (int w = threadIdx.x; w < HWORDS; w += 256) bins[w] = 0u;
    __syncthreads();
    for (int i = threadIdx.x; i < HCHUNK; i += 256) {
        int v = arr[i];
        if ((v >> 15) == rg) {
            int b = v & 32767;
            atomicAdd(&bins[b >> 1], 1u << ((b & 1) * 16));   // LDS, no return
        }
    }
    __syncthreads();
    unsigned int* out = slab32 + ((size_t)((job * 2 + rg) * HC + chunk)) * HWORDS;
    for (int w = threadIdx.x; w < HWORDS; w += 256) out[w] = bins[w];
}

// ---------------- slab reduce -> degrees/norms; dst-slabs -> per-chunk prefixes
__global__ __launch_bounds__(256) void degnorm_kernel(unsigned short* __restrict__ slab16,
                                                      int* __restrict__ idI,
                                                      float* __restrict__ outnorm,
                                                      float* __restrict__ innorm) {
    int gid = blockIdx.x * 256 + threadIdx.x;
    if (gid >= 6 * NODES) return;
    int j = gid / NODES, node = gid - j * NODES;
    int rg = node >> 15, b = node & 32767;
    size_t base = ((size_t)((j * 2 + rg) * HC)) << 15;       // *32768 u16 elements
    if (j < 3) {
        int sum = 0;
#pragma unroll 4
        for (int c = 0; c < HC; ++c) sum += slab16[base + ((size_t)c << 15) + b];
        outnorm[j * NODES + node] = rsqrtf(fmaxf((float)sum, 1.0f));
    } else {
        int run = 0;
#pragma unroll 4
        for (int c = 0; c < HC; ++c) {
            size_t idx = base + ((size_t)c << 15) + b;
            int v = slab16[idx];
            slab16[idx] = (unsigned short)run;               // per-chunk prefix (<=deg, fits u16)
            run += v;
        }
        idI[(j - 3) * NODES + node] = run;
        innorm[(j - 3) * NODES + node] = rsqrtf(fmaxf((float)run, 1.0f));
    }
}

// ---------------- exclusive scan over idI (3 kernels) ----------------
__global__ __launch_bounds__(256) void scan_sums_kernel(const int* __restrict__ idI,
                                                        int* __restrict__ partials) {
    __shared__ int s[256];
    int i = blockIdx.x * 256 + threadIdx.x;
    s[threadIdx.x] = (i < SEGS) ? idI[i] : 0;
    __syncthreads();
    for (int off = 128; off > 0; off >>= 1) {
        if (threadIdx.x < off) s[threadIdx.x] += s[threadIdx.x + off];
        __syncthreads();
    }
    if (threadIdx.x == 0) partials[blockIdx.x] = s[0];
}

__global__ __launch_bounds__(1024) void scan_partials_kernel(int* __restrict__ partials) {
    __shared__ int s[1024];
    int tid = threadIdx.x;
    int v = (tid < NBLK) ? partials[tid] : 0;
    s[tid] = v;
    __syncthreads();
    for (int off = 1; off < 1024; off <<= 1) {
        int t = s[tid];
        int add = (tid >= off) ? s[tid - off] : 0;
        __syncthreads();
        s[tid] = t + add;
        __syncthreads();
    }
    if (tid < NBLK) partials[tid] = s[tid] - v;   // exclusive
}

__global__ __launch_bounds__(256) void scan_write_kernel(const int* __restrict__ idI,
                                                         const int* __restrict__ partials,
                                                         int* __restrict__ offs) {
    __shared__ int s[256];
    int tid = threadIdx.x;
    int i = blockIdx.x * 256 + tid;
    int v = (i < SEGS) ? idI[i] : 0;
    s[tid] = v;
    __syncthreads();
    for (int off = 1; off < 256; off <<= 1) {
        int t = s[tid];
        int add = (tid >= off) ? s[tid - off] : 0;
        __syncthreads();
        s[tid] = t + add;
        __syncthreads();
    }
    if (i < SEGS) offs[i] = partials[blockIdx.x] + (s[tid] - v);
}

// ---------------- CSR fill via LDS cursors + per-chunk slab prefixes ----------------
// pos = offs[seg] + slab_prefix[chunk][bin] + lds_local_rank. Zero global atomics.
__global__ __launch_bounds__(256) void fill2_kernel(const int* __restrict__ src,
                                                    const int* __restrict__ dst,
                                                    const int* __restrict__ offs,
                                                    const unsigned short* __restrict__ slab16,
                                                    int* __restrict__ edge_src) {
    __shared__ unsigned int cur[HWORDS];           // 64 KB u16-packed cursors
    int chunk = blockIdx.x, r = blockIdx.y, rg = blockIdx.z;
    for (int w = threadIdx.x; w < HWORDS; w += 256) cur[w] = 0u;
    __syncthreads();
    size_t ebase = (size_t)r * NEDGE + (size_t)chunk * HCHUNK;
    const unsigned short* pre = slab16 + (((size_t)(((3 + r) * 2 + rg) * HC + chunk)) << 15);
    for (int i = threadIdx.x; i < HCHUNK; i += 256) {
        int d = dst[ebase + i];
        if ((d >> 15) == rg) {
            int b = d & 32767;
            unsigned int old = atomicAdd(&cur[b >> 1], 1u << ((b & 1) * 16));
            int local = (int)((old >> ((b & 1) * 16)) & 0xffffu);
            int pos = offs[r * NODES + d] + (int)pre[b] + local;
            edge_src[pos] = src[ebase + i];
        }
    }
}

// ---------------- layer 1 GEMM, ALL relations in one pass ----------------
__global__ __launch_bounds__(256, 4) void gemm1_kernel(const float* __restrict__ x,
                                                       const float* __restrict__ W1,
                                                       const float* __restrict__ outnorm,
                                                       float* __restrict__ h) {
    int j  = threadIdx.x & 63;
    int wv = threadIdx.x >> 6;
    int n0 = (blockIdx.x * 4 + wv) * 8;
    if (n0 + 8 > NODES) n0 = NODES - 8;       // tail waves redo rows (same values)
    const float* xb = x + (size_t)n0 * FIN;

    float acc[RELS][8];
#pragma unroll
    for (int r = 0; r < RELS; ++r)
#pragma unroll
        for (int i = 0; i < 8; ++i) acc[r][i] = 0.f;

#pragma unroll 1
    for (int k4 = 0; k4 < FIN / 4; ++k4) {
        float4 a[8];
#pragma unroll
        for (int i = 0; i < 8; ++i)
            a[i] = *(const float4*)(xb + (size_t)i * FIN + k4 * 4);
#pragma unroll
        for (int r = 0; r < RELS; ++r) {
            const float* wp = W1 + (size_t)r * FIN * FHID + (size_t)k4 * 4 * FHID + j;
            float w0 = wp[0], w1 = wp[FHID], w2 = wp[2 * FHID], w3 = wp[3 * FHID];
#pragma unroll
            for (int i = 0; i < 8; ++i) {
                acc[r][i] = fmaf(a[i].x, w0, acc[r][i]);
                acc[r][i] = fmaf(a[i].y, w1, acc[r][i]);
                acc[r][i] = fmaf(a[i].z, w2, acc[r][i]);
                acc[r][i] = fmaf(a[i].w, w3, acc[r][i]);
            }
        }
    }

#pragma unroll
    for (int r = 0; r < RELS; ++r) {
        const float* on = outnorm + r * NODES + n0;
        float* hb = h + ((size_t)r * NODES + n0) * FHID + j;
#pragma unroll
        for (int i = 0; i < 8; ++i) hb[(size_t)i * FHID] = acc[r][i] * on[i];
    }
}

// ---------------- layer 1 gather ----------------
__global__ __launch_bounds__(256) void gather1_kernel(const float* __restrict__ h,
                                                      const int* __restrict__ es,
                                                      const int* __restrict__ offs,
                                                      const int* __restrict__ cnt,
                                                      const float* __restrict__ innorm,
                                                      const float* __restrict__ b1,
                                                      float* __restrict__ B) {
    int lane = threadIdx.x & 63;
    int wv   = threadIdx.x >> 6;
    int d    = blockIdx.x * 4 + wv;           // NODES % 4 == 0
    int q    = lane & 15;                     // float4 slot within row
    int e4   = lane >> 4;                     // which of 4 edges
    float4 tot = {0.f, 0.f, 0.f, 0.f};
#pragma unroll
    for (int r = 0; r < RELS; ++r) {
        int seg = r * NODES + d;
        int o = offs[seg], c = cnt[seg];
        const float* Ar = h + (size_t)r * NODES * FHID;
        float4 s0 = {0.f, 0.f, 0.f, 0.f}, s1 = {0.f, 0.f, 0.f, 0.f};
        int t = 0;
        for (; t + 8 <= c; t += 8) {
            int ia = es[o + t + e4];
            int ib = es[o + t + 4 + e4];
            float4 va = *(const float4*)(Ar + (size_t)ia * FHID + q * 4);
            float4 vb = *(const float4*)(Ar + (size_t)ib * FHID + q * 4);
            s0.x += va.x; s0.y += va.y; s0.z += va.z; s0.w += va.w;
            s1.x += vb.x; s1.y += vb.y; s1.z += vb.z; s1.w += vb.w;
        }
        if (t + 4 <= c) {
            int ia = es[o + t + e4];
            float4 va = *(const float4*)(Ar + (size_t)ia * FHID + q * 4);
            s0.x += va.x; s0.y += va.y; s0.z += va.z; s0.w += va.w;
            t += 4;
        }
        int rem = c - t;
        if (e4 < rem) {
            int ia = es[o + t + e4];
            float4 va = *(const float4*)(Ar + (size_t)ia * FHID + q * 4);
            s1.x += va.x; s1.y += va.y; s1.z += va.z; s1.w += va.w;
        }
        float inr = innorm[seg];
        tot.x = fmaf(inr, s0.x + s1.x, tot.x);
        tot.y = fmaf(inr, s0.y + s1.y, tot.y);
        tot.z = fmaf(inr, s0.z + s1.z, tot.z);
        tot.w = fmaf(inr, s0.w + s1.w, tot.w);
    }
    tot.x += __shfl_xor(tot.x, 16); tot.y += __shfl_xor(tot.y, 16);
    tot.z += __shfl_xor(tot.z, 16); tot.w += __shfl_xor(tot.w, 16);
    tot.x += __shfl_xor(tot.x, 32); tot.y += __shfl_xor(tot.y, 32);
    tot.z += __shfl_xor(tot.z, 32); tot.w += __shfl_xor(tot.w, 32);
    if (lane < 16) {
        float4 bs0 = ((const float4*)b1)[q];
        float4 bs1 = ((const float4*)(b1 + FHID))[q];
        float4 bs2 = ((const float4*)(b1 + 2 * FHID))[q];
        float4 o4;
        o4.x = fmaxf(tot.x + bs0.x + bs1.x + bs2.x, 0.f);
        o4.y = fmaxf(tot.y + bs0.y + bs1.y + bs2.y, 0.f);
        o4.z = fmaxf(tot.z + bs0.z + bs1.z + bs2.z, 0.f);
        o4.w = fmaxf(tot.w + bs0.w + bs1.w + bs2.w, 0.f);
        *(float4*)(B + (size_t)d * FHID + q * 4) = o4;
    }
}

// ---------------- layer 2 gather ----------------
__global__ __launch_bounds__(256) void gather2_kernel(const float* __restrict__ h1,
                                                      const int* __restrict__ es,
                                                      const int* __restrict__ offs,
                                                      const int* __restrict__ cnt,
                                                      const float* __restrict__ outnorm,
                                                      const float* __restrict__ innorm,
                                                      float* __restrict__ A) {
    int lane = threadIdx.x & 63;
    int wv   = threadIdx.x >> 6;
    int d    = blockIdx.x * 4 + wv;
    int r    = blockIdx.y;
    int q    = lane & 15;
    int e4   = lane >> 4;
    int seg = r * NODES + d;
    int o = offs[seg], c = cnt[seg];
    const float* on = outnorm + r * NODES;
    float4 s0 = {0.f, 0.f, 0.f, 0.f}, s1 = {0.f, 0.f, 0.f, 0.f};
    int t = 0;
    for (; t + 8 <= c; t += 8) {
        int ia = es[o + t + e4];
        int ib = es[o + t + 4 + e4];
        float wa = on[ia], wb = on[ib];
        float4 va = *(const float4*)(h1 + (size_t)ia * FHID + q * 4);
        float4 vb = *(const float4*)(h1 + (size_t)ib * FHID + q * 4);
        s0.x = fmaf(wa, va.x, s0.x); s0.y = fmaf(wa, va.y, s0.y);
        s0.z = fmaf(wa, va.z, s0.z); s0.w = fmaf(wa, va.w, s0.w);
        s1.x = fmaf(wb, vb.x, s1.x); s1.y = fmaf(wb, vb.y, s1.y);
        s1.z = fmaf(wb, vb.z, s1.z); s1.w = fmaf(wb, vb.w, s1.w);
    }
    if (t + 4 <= c) {
        int ia = es[o + t + e4];
        float wa = on[ia];
        float4 va = *(const float4*)(h1 + (size_t)ia * FHID + q * 4);
        s0.x = fmaf(wa, va.x, s0.x); s0.y = fmaf(wa, va.y, s0.y);
        s0.z = fmaf(wa, va.z, s0.z); s0.w = fmaf(wa, va.w, s0.w);
        t += 4;
    }
    int rem = c - t;
    if (e4 < rem) {
        int ia = es[o + t + e4];
        float wa = on[ia];
        float4 va = *(const float4*)(h1 + (size_t)ia * FHID + q * 4);
        s1.x = fmaf(wa, va.x, s1.x); s1.y = fmaf(wa, va.y, s1.y);
        s1.z = fmaf(wa, va.z, s1.z); s1.w = fmaf(wa, va.w, s1.w);
    }
    float4 s = {s0.x + s1.x, s0.y + s1.y, s0.z + s1.z, s0.w + s1.w};
    s.x += __shfl_xor(s.x, 16); s.y += __shfl_xor(s.y, 16);
    s.z += __shfl_xor(s.z, 16); s.w += __shfl_xor(s.w, 16);
    s.x += __shfl_xor(s.x, 32); s.y += __shfl_xor(s.y, 32);
    s.z += __shfl_xor(s.z, 32); s.w += __shfl_xor(s.w, 32);
    if (lane < 16) {
        float inr = innorm[seg];
        float4 o4 = {inr * s.x, inr * s.y, inr * s.z, inr * s.w};
        *(float4*)(A + (size_t)seg * FHID + q * 4) = o4;
    }
}

// ---------------- layer 2 GEMM + combine ----------------
__global__ __launch_bounds__(256, 4) void out_kernel(const float* __restrict__ agg2,
                                                     const float* __restrict__ W2,
                                                     const float* __restrict__ b2,
                                                     float* __restrict__ out) {
    int j  = threadIdx.x & 63;
    int wv = threadIdx.x >> 6;
    int n0 = (blockIdx.x * 4 + wv) * 8;
    if (n0 + 8 > NODES) n0 = NODES - 8;
    float bsum = b2[j] + b2[FOUT + j] + b2[2 * FOUT + j];
    float acc[8];
#pragma unroll
    for (int i = 0; i < 8; ++i) acc[i] = bsum;

#pragma unroll 1
    for (int kk = 0; kk < RELS * FHID / 4; ++kk) {   // 48 steps
        int r = kk >> 4, k4 = kk & 15;
        const float* ap = agg2 + ((size_t)r * NODES + n0) * FHID + k4 * 4;
        float4 a[8];
#pragma unroll
        for (int i = 0; i < 8; ++i) a[i] = *(const float4*)(ap + (size_t)i * FHID);
        const float* wp = W2 + (size_t)r * FHID * FOUT + (size_t)k4 * 4 * FOUT + j;
        float w0 = wp[0], w1 = wp[FOUT], w2 = wp[2 * FOUT], w3 = wp[3 * FOUT];
#pragma unroll
        for (int i = 0; i < 8; ++i) {
            acc[i] = fmaf(a[i].x, w0, acc[i]);
            acc[i] = fmaf(a[i].y, w1, acc[i]);
            acc[i] = fmaf(a[i].z, w2, acc[i]);
            acc[i] = fmaf(a[i].w, w3, acc[i]);
        }
    }

    float* ob = out + (size_t)n0 * FOUT + j;
#pragma unroll
    for (int i = 0; i < 8; ++i) ob[(size_t)i * FOUT] = acc[i];
}

extern "C" void kernel_launch(void* const* d_in, const int* in_sizes, int n_in,
                              void* d_out, int out_size, void* d_ws, size_t ws_size,
                              hipStream_t stream) {
    const float* x   = (const float*)d_in[0];   // [N,128]
    const float* W1  = (const float*)d_in[1];   // [3,128,64]
    const float* b1  = (const float*)d_in[2];   // [3,64]
    const float* W2  = (const float*)d_in[3];   // [3,64,64]
    const float* b2  = (const float*)d_in[4];   // [3,64]
    const int*   src = (const int*)d_in[5];     // [3,E]
    const int*   dst = (const int*)d_in[6];     // [3,E]
    float* out = (float*)d_out;                 // [N,64]

    // workspace: idI | offs | partials(1024) | edge_src | outnorm | innorm | A | B
    int*   idI      = (int*)d_ws;
    int*   offs     = idI + SEGS;
    int*   partials = offs + SEGS;
    int*   edge_src = partials + 1024;
    float* outnorm  = (float*)(edge_src + (size_t)RELS * NEDGE);
    float* innorm   = outnorm + SEGS;
    float* A        = innorm + SEGS;                  // [3,N,64] layer-1 h / layer-2 agg
    float* B        = A + (size_t)SEGS * FHID;        // [N,64]   layer-1 output (h1)
    // slabs (25.2 MB) alias the A region: consumed before gemm1 overwrites A
    unsigned int*   slab32 = (unsigned int*)A;
    unsigned short* slab16 = (unsigned short*)A;

    const int GB = (NODES / 8 + 3) / 4;               // 1563 blocks of 4 waves x 8 rows

    // degrees + norms + CSR, all without global atomics
    hist_kernel<<<dim3(HC, 6, 2), 256, 0, stream>>>(src, dst, slab32);
    degnorm_kernel<<<(6 * NODES + 255) / 256, 256, 0, stream>>>(slab16, idI, outnorm, innorm);
    scan_sums_kernel<<<NBLK, 256, 0, stream>>>(idI, partials);
    scan_partials_kernel<<<1, 1024, 0, stream>>>(partials);
    scan_write_kernel<<<NBLK, 256, 0, stream>>>(idI, partials, offs);
    fill2_kernel<<<dim3(HC, RELS, 2), 256, 0, stream>>>(src, dst, offs, slab16, edge_src);

    // layer 1 (gemm over ALL relations in one pass)
    gemm1_kernel<<<GB, 256, 0, stream>>>(x, W1, outnorm, A);
    gather1_kernel<<<NODES / 4, 256, 0, stream>>>(A, edge_src, offs, idI, innorm, b1, B);

    // layer 2
    gather2_kernel<<<dim3(NODES / 4, RELS), 256, 0, stream>>>(B, edge_src, offs, idI, outnorm, innorm, A);
    out_kernel<<<GB, 256, 0, stream>>>(A, W2, b2, out);
}

// Round 8
// 350.598 us; speedup vs baseline: 2.0156x; 1.3904x over previous
//
#include <hip/hip_runtime.h>

#define NODES 50000
#define RELS  3
#define NEDGE 600000
#define FIN   128
#define FHID  64
#define FOUT  64
#define SEGS  (RELS * NODES)            // 150000 (rel, dst) segments
#define NBLK  ((SEGS + 255) / 256)      // 586 scan blocks

#define HC     32                       // histogram chunks per edge array
#define HCHUNK (NEDGE / HC)             // 18750 (exact)
#define HWORDS 16384                    // 32768 u16 bins packed in u32 words (64 KB LDS)

typedef _Float16 half8 __attribute__((ext_vector_type(8)));
typedef float   floatx4 __attribute__((ext_vector_type(4)));

// ---------------- LDS-staged histogram: no global atomics ----------------
__global__ __launch_bounds__(256) void hist_kernel(const int* __restrict__ src,
                                                   const int* __restrict__ dst,
                                                   unsigned int* __restrict__ slab32) {
    __shared__ unsigned int bins[HWORDS];          // 64 KB, u16-packed counts
    int chunk = blockIdx.x, job = blockIdx.y, rg = blockIdx.z;
    const int* arr = (job < 3 ? src + (size_t)job * NEDGE
                              : dst + (size_t)(job - 3) * NEDGE) + (size_t)chunk * HCHUNK;
    for (int w = threadIdx.x; w < HWORDS; w += 256) bins[w] = 0u;
    __syncthreads();
    for (int i = threadIdx.x; i < HCHUNK; i += 256) {
        int v = arr[i];
        if ((v >> 15) == rg) {
            int b = v & 32767;
            atomicAdd(&bins[b >> 1], 1u << ((b & 1) * 16));   // LDS, no return
        }
    }
    __syncthreads();
    unsigned int* out = slab32 + ((size_t)((job * 2 + rg) * HC + chunk)) * HWORDS;
    for (int w = threadIdx.x; w < HWORDS; w += 256) out[w] = bins[w];
}

// ---------------- slab reduce -> degrees/norms; dst-slabs -> per-chunk prefixes
__global__ __launch_bounds__(256) void degnorm_kernel(unsigned short* __restrict__ slab16,
                                                      int* __restrict__ idI,
                                                      float* __restrict__ outnorm,
                                                      float* __restrict__ innorm) {
    int gid = blockIdx.x * 256 + threadIdx.x;
    if (gid >= 6 * NODES) return;
    int j = gid / NODES, node = gid - j * NODES;
    int rg = node >> 15, b = node & 32767;
    size_t base = ((size_t)((j * 2 + rg) * HC)) << 15;
    if (j < 3) {
        int sum = 0;
#pragma unroll 4
        for (int c = 0; c < HC; ++c) sum += slab16[base + ((size_t)c << 15) + b];
        outnorm[j * NODES + node] = rsqrtf(fmaxf((float)sum, 1.0f));
    } else {
        int run = 0;
#pragma unroll 4
        for (int c = 0; c < HC; ++c) {
            size_t idx = base + ((size_t)c << 15) + b;
            int v = slab16[idx];
            slab16[idx] = (unsigned short)run;
            run += v;
        }
        idI[(j - 3) * NODES + node] = run;
        innorm[(j - 3) * NODES + node] = rsqrtf(fmaxf((float)run, 1.0f));
    }
}

// ---------------- exclusive scan over idI (3 kernels) ----------------
__global__ __launch_bounds__(256) void scan_sums_kernel(const int* __restrict__ idI,
                                                        int* __restrict__ partials) {
    __shared__ int s[256];
    int i = blockIdx.x * 256 + threadIdx.x;
    s[threadIdx.x] = (i < SEGS) ? idI[i] : 0;
    __syncthreads();
    for (int off = 128; off > 0; off >>= 1) {
        if (threadIdx.x < off) s[threadIdx.x] += s[threadIdx.x + off];
        __syncthreads();
    }
    if (threadIdx.x == 0) partials[blockIdx.x] = s[0];
}

__global__ __launch_bounds__(1024) void scan_partials_kernel(int* __restrict__ partials) {
    __shared__ int s[1024];
    int tid = threadIdx.x;
    int v = (tid < NBLK) ? partials[tid] : 0;
    s[tid] = v;
    __syncthreads();
    for (int off = 1; off < 1024; off <<= 1) {
        int t = s[tid];
        int add = (tid >= off) ? s[tid - off] : 0;
        __syncthreads();
        s[tid] = t + add;
        __syncthreads();
    }
    if (tid < NBLK) partials[tid] = s[tid] - v;   // exclusive
}

__global__ __launch_bounds__(256) void scan_write_kernel(const int* __restrict__ idI,
                                                         const int* __restrict__ partials,
                                                         int* __restrict__ offs) {
    __shared__ int s[256];
    int tid = threadIdx.x;
    int i = blockIdx.x * 256 + tid;
    int v = (i < SEGS) ? idI[i] : 0;
    s[tid] = v;
    __syncthreads();
    for (int off = 1; off < 256; off <<= 1) {
        int t = s[tid];
        int add = (tid >= off) ? s[tid - off] : 0;
        __syncthreads();
        s[tid] = t + add;
        __syncthreads();
    }
    if (i < SEGS) offs[i] = partials[blockIdx.x] + (s[tid] - v);
}

// ---------------- CSR fill via LDS cursors + per-chunk slab prefixes ----------------
__global__ __launch_bounds__(256) void fill2_kernel(const int* __restrict__ src,
                                                    const int* __restrict__ dst,
                                                    const int* __restrict__ offs,
                                                    const unsigned short* __restrict__ slab16,
                                                    int* __restrict__ edge_src) {
    __shared__ unsigned int cur[HWORDS];           // 64 KB u16-packed cursors
    int chunk = blockIdx.x, r = blockIdx.y, rg = blockIdx.z;
    for (int w = threadIdx.x; w < HWORDS; w += 256) cur[w] = 0u;
    __syncthreads();
    size_t ebase = (size_t)r * NEDGE + (size_t)chunk * HCHUNK;
    const unsigned short* pre = slab16 + (((size_t)(((3 + r) * 2 + rg) * HC + chunk)) << 15);
    for (int i = threadIdx.x; i < HCHUNK; i += 256) {
        int d = dst[ebase + i];
        if ((d >> 15) == rg) {
            int b = d & 32767;
            unsigned int old = atomicAdd(&cur[b >> 1], 1u << ((b & 1) * 16));
            int local = (int)((old >> ((b & 1) * 16)) & 0xffffu);
            int pos = offs[r * NODES + d] + (int)pre[b] + local;
            edge_src[pos] = src[ebase + i];
        }
    }
}

// ---------------- weight convert: W1 -> fp16 [r][j][k], W2 -> fp16 [r][j][k]
__global__ __launch_bounds__(256) void convw_kernel(const float* __restrict__ W1,
                                                    const float* __restrict__ W2,
                                                    _Float16* __restrict__ W1t,
                                                    _Float16* __restrict__ W2t) {
    int gid = blockIdx.x * 256 + threadIdx.x;
    if (gid < RELS * FIN * FHID) {                 // 24576
        int r = gid / (FIN * FHID);
        int rem = gid - r * FIN * FHID;
        int k = rem / FHID, j = rem - k * FHID;
        W1t[((size_t)r * FHID + j) * FIN + k] = (_Float16)W1[gid];
    }
    if (gid < RELS * FHID * FOUT) {                // 12288
        int r = gid / (FHID * FOUT);
        int rem = gid - r * FHID * FOUT;
        int k = rem / FOUT, j = rem - k * FOUT;
        W2t[((size_t)r * FOUT + j) * FHID + k] = (_Float16)W2[gid];
    }
}

// ---------------- layer 1 GEMM via MFMA fp16 ----------------
// Wave = 16 nodes x 192 cols (12 C-frags). A = x rows (fp32->fp16 in-reg),
// B = W1t[j][k] fp16. h output fp16 with outnorm folded.
__global__ __launch_bounds__(256, 4) void gemm1_kernel(const float* __restrict__ x,
                                                       const _Float16* __restrict__ W1t,
                                                       const float* __restrict__ outnorm,
                                                       _Float16* __restrict__ h) {
    int lane = threadIdx.x & 63;
    int wv   = threadIdx.x >> 6;
    int m = lane & 15, quad = lane >> 4;
    int n0 = (blockIdx.x * 4 + wv) * 16;
    if (n0 + 16 > NODES) n0 = NODES - 16;          // tail waves duplicate rows (same values)
    const float* xrow = x + (size_t)(n0 + m) * FIN + quad * 8;

    floatx4 acc[12];
#pragma unroll
    for (int t = 0; t < 12; ++t) acc[t] = (floatx4){0.f, 0.f, 0.f, 0.f};

#pragma unroll 1
    for (int ks = 0; ks < 4; ++ks) {               // K step of 32
        float4 xa = *(const float4*)(xrow + ks * 32);
        float4 xb = *(const float4*)(xrow + ks * 32 + 4);
        half8 a;
        a[0] = (_Float16)xa.x; a[1] = (_Float16)xa.y;
        a[2] = (_Float16)xa.z; a[3] = (_Float16)xa.w;
        a[4] = (_Float16)xb.x; a[5] = (_Float16)xb.y;
        a[6] = (_Float16)xb.z; a[7] = (_Float16)xb.w;
#pragma unroll
        for (int jt = 0; jt < 12; ++jt) {          // W1t flat: [192][128]
            const _Float16* bp = W1t + ((size_t)jt * 16 + m) * FIN + ks * 32 + quad * 8;
            half8 b = *(const half8*)bp;
            acc[jt] = __builtin_amdgcn_mfma_f32_16x16x32_f16(a, b, acc[jt], 0, 0, 0);
        }
    }

#pragma unroll
    for (int jt = 0; jt < 12; ++jt) {
        int r = jt >> 2;
        int j = (jt & 3) * 16 + m;                 // D col = lane&15
        _Float16* hb = h + (size_t)r * NODES * FHID;
        const float* on = outnorm + r * NODES;
#pragma unroll
        for (int reg = 0; reg < 4; ++reg) {
            int node = n0 + quad * 4 + reg;        // D row = quad*4+reg
            hb[(size_t)node * FHID + j] = (_Float16)(acc[jt][reg] * on[node]);
        }
    }
}

// ---------------- layer 1 gather (fp16 rows, 128 B) ----------------
// Wave per dst node: lanes = 8 edges x 8 half8-slots; dual accumulator chains.
__global__ __launch_bounds__(256) void gather1_kernel(const _Float16* __restrict__ h,
                                                      const int* __restrict__ es,
                                                      const int* __restrict__ offs,
                                                      const int* __restrict__ cnt,
                                                      const float* __restrict__ innorm,
                                                      const float* __restrict__ b1,
                                                      _Float16* __restrict__ B) {
    int lane = threadIdx.x & 63;
    int wv   = threadIdx.x >> 6;
    int d    = blockIdx.x * 4 + wv;
    int q    = lane & 7;                           // half8 slot
    int e8   = lane >> 3;                          // edge within batch of 8
    float tot[8] = {0.f, 0.f, 0.f, 0.f, 0.f, 0.f, 0.f, 0.f};
#pragma unroll
    for (int r = 0; r < RELS; ++r) {
        int seg = r * NODES + d;
        int o = offs[seg], c = cnt[seg];
        const _Float16* Ar = h + (size_t)r * NODES * FHID;
        float s0[8] = {0.f, 0.f, 0.f, 0.f, 0.f, 0.f, 0.f, 0.f};
        float s1[8] = {0.f, 0.f, 0.f, 0.f, 0.f, 0.f, 0.f, 0.f};
        int t = 0;
        for (; t + 16 <= c; t += 16) {
            int ia = es[o + t + e8];
            int ib = es[o + t + 8 + e8];
            half8 va = *(const half8*)(Ar + (size_t)ia * FHID + q * 8);
            half8 vb = *(const half8*)(Ar + (size_t)ib * FHID + q * 8);
#pragma unroll
            for (int i = 0; i < 8; ++i) { s0[i] += (float)va[i]; s1[i] += (float)vb[i]; }
        }
        if (t + 8 <= c) {
            int ia = es[o + t + e8];
            half8 va = *(const half8*)(Ar + (size_t)ia * FHID + q * 8);
#pragma unroll
            for (int i = 0; i < 8; ++i) s0[i] += (float)va[i];
            t += 8;
        }
        int rem = c - t;
        if (e8 < rem) {
            int ia = es[o + t + e8];
            half8 va = *(const half8*)(Ar + (size_t)ia * FHID + q * 8);
#pragma unroll
            for (int i = 0; i < 8; ++i) s1[i] += (float)va[i];
        }
        float inr = innorm[seg];
#pragma unroll
        for (int i = 0; i < 8; ++i) tot[i] = fmaf(inr, s0[i] + s1[i], tot[i]);
    }
#pragma unroll
    for (int i = 0; i < 8; ++i) {
        tot[i] += __shfl_xor(tot[i], 8);
        tot[i] += __shfl_xor(tot[i], 16);
        tot[i] += __shfl_xor(tot[i], 32);
    }
    if (lane < 8) {
        half8 o8;
#pragma unroll
        for (int i = 0; i < 8; ++i) {
            int j = q * 8 + i;
            float bs = b1[j] + b1[FHID + j] + b1[2 * FHID + j];
            o8[i] = (_Float16)fmaxf(tot[i] + bs, 0.f);
        }
        *(half8*)(B + (size_t)d * FHID + q * 8) = o8;
    }
}

// ---------------- layer 2 gather: A2[r][d][:] = innorm * sum_e outnorm[src]*h1[src][:]
__global__ __launch_bounds__(256) void gather2_kernel(const _Float16* __restrict__ h1,
                                                      const int* __restrict__ es,
                                                      const int* __restrict__ offs,
                                                      const int* __restrict__ cnt,
                                                      const float* __restrict__ outnorm,
                                                      const float* __restrict__ innorm,
                                                      _Float16* __restrict__ A2) {
    int lane = threadIdx.x & 63;
    int wv   = threadIdx.x >> 6;
    int d    = blockIdx.x * 4 + wv;
    int r    = blockIdx.y;
    int q    = lane & 7;
    int e8   = lane >> 3;
    int seg = r * NODES + d;
    int o = offs[seg], c = cnt[seg];
    const float* on = outnorm + r * NODES;
    float s0[8] = {0.f, 0.f, 0.f, 0.f, 0.f, 0.f, 0.f, 0.f};
    float s1[8] = {0.f, 0.f, 0.f, 0.f, 0.f, 0.f, 0.f, 0.f};
    int t = 0;
    for (; t + 16 <= c; t += 16) {
        int ia = es[o + t + e8];
        int ib = es[o + t + 8 + e8];
        float wa = on[ia], wb = on[ib];
        half8 va = *(const half8*)(h1 + (size_t)ia * FHID + q * 8);
        half8 vb = *(const half8*)(h1 + (size_t)ib * FHID + q * 8);
#pragma unroll
        for (int i = 0; i < 8; ++i) {
            s0[i] = fmaf(wa, (float)va[i], s0[i]);
            s1[i] = fmaf(wb, (float)vb[i], s1[i]);
        }
    }
    if (t + 8 <= c) {
        int ia = es[o + t + e8];
        float wa = on[ia];
        half8 va = *(const half8*)(h1 + (size_t)ia * FHID + q * 8);
#pragma unroll
        for (int i = 0; i < 8; ++i) s0[i] = fmaf(wa, (float)va[i], s0[i]);
        t += 8;
    }
    int rem = c - t;
    if (e8 < rem) {
        int ia = es[o + t + e8];
        float wa = on[ia];
        half8 va = *(const half8*)(h1 + (size_t)ia * FHID + q * 8);
#pragma unroll
        for (int i = 0; i < 8; ++i) s1[i] = fmaf(wa, (float)va[i], s1[i]);
    }
    float tot[8];
#pragma unroll
    for (int i = 0; i < 8; ++i) {
        tot[i] = s0[i] + s1[i];
        tot[i] += __shfl_xor(tot[i], 8);
        tot[i] += __shfl_xor(tot[i], 16);
        tot[i] += __shfl_xor(tot[i], 32);
    }
    if (lane < 8) {
        float inr = innorm[seg];
        half8 o8;
#pragma unroll
        for (int i = 0; i < 8; ++i) o8[i] = (_Float16)(inr * tot[i]);
        *(half8*)(A2 + (size_t)seg * FHID + q * 8) = o8;
    }
}

// ---------------- layer 2 GEMM via MFMA fp16: out = sum_r A2[r] @ W2[r] + bias
__global__ __launch_bounds__(256, 4) void out_kernel(const _Float16* __restrict__ A2,
                                                     const _Float16* __restrict__ W2t,
                                                     const float* __restrict__ b2,
                                                     float* __restrict__ out) {
    int lane = threadIdx.x & 63;
    int wv   = threadIdx.x >> 6;
    int m = lane & 15, quad = lane >> 4;
    int n0 = (blockIdx.x * 4 + wv) * 16;
    if (n0 + 16 > NODES) n0 = NODES - 16;

    floatx4 acc[4];
#pragma unroll
    for (int t = 0; t < 4; ++t) acc[t] = (floatx4){0.f, 0.f, 0.f, 0.f};

#pragma unroll 1
    for (int kk = 0; kk < 6; ++kk) {               // (rel, 32-K-step)
        int r = kk >> 1, kb = (kk & 1) * 32;
        const _Float16* ap = A2 + ((size_t)r * NODES + n0 + m) * FHID + kb + quad * 8;
        half8 a = *(const half8*)ap;
#pragma unroll
        for (int jt = 0; jt < 4; ++jt) {
            const _Float16* bp = W2t + ((size_t)(r * FOUT + jt * 16 + m)) * FHID + kb + quad * 8;
            half8 b = *(const half8*)bp;
            acc[jt] = __builtin_amdgcn_mfma_f32_16x16x32_f16(a, b, acc[jt], 0, 0, 0);
        }
    }

#pragma unroll
    for (int jt = 0; jt < 4; ++jt) {
        int j = jt * 16 + m;
        float bs = b2[j] + b2[FOUT + j] + b2[2 * FOUT + j];
#pragma unroll
        for (int reg = 0; reg < 4; ++reg) {
            int node = n0 + quad * 4 + reg;
            out[(size_t)node * FOUT + j] = acc[jt][reg] + bs;
        }
    }
}

extern "C" void kernel_launch(void* const* d_in, const int* in_sizes, int n_in,
                              void* d_out, int out_size, void* d_ws, size_t ws_size,
                              hipStream_t stream) {
    const float* x   = (const float*)d_in[0];   // [N,128]
    const float* W1  = (const float*)d_in[1];   // [3,128,64]
    const float* b1  = (const float*)d_in[2];   // [3,64]
    const float* W2  = (const float*)d_in[3];   // [3,64,64]
    const float* b2  = (const float*)d_in[4];   // [3,64]
    const int*   src = (const int*)d_in[5];     // [3,E]
    const int*   dst = (const int*)d_in[6];     // [3,E]
    float* out = (float*)d_out;                 // [N,64]

    // ws: idI | offs | partials | edge_src | outnorm | innorm | W1t | W2t | h | B | A2  (~54.5 MB)
    int*   idI      = (int*)d_ws;
    int*   offs     = idI + SEGS;
    int*   partials = offs + SEGS;
    int*   edge_src = partials + 1024;
    float* outnorm  = (float*)(edge_src + (size_t)RELS * NEDGE);
    float* innorm   = outnorm + SEGS;
    _Float16* W1t   = (_Float16*)(innorm + SEGS);            // [3][64][128]
    _Float16* W2t   = W1t + (size_t)RELS * FHID * FIN;       // [3][64][64]
    _Float16* h     = W2t + (size_t)RELS * FHID * FOUT;      // [3][N][64] fp16
    _Float16* B     = h + (size_t)SEGS * FHID;               // [N][64] fp16
    _Float16* A2    = B + (size_t)NODES * FHID;              // [3][N][64] fp16
    // 25.2 MB slab aliases h|B (consumed by fill2 before gemm1/gather1 write them)
    unsigned int*   slab32 = (unsigned int*)h;
    unsigned short* slab16 = (unsigned short*)h;

    const int GW = ((NODES / 16) + 4) / 4;        // 782 blocks of 4 waves x 16 nodes

    // CSR build + norms, no global atomics
    hist_kernel<<<dim3(HC, 6, 2), 256, 0, stream>>>(src, dst, slab32);
    degnorm_kernel<<<(6 * NODES + 255) / 256, 256, 0, stream>>>(slab16, idI, outnorm, innorm);
    scan_sums_kernel<<<NBLK, 256, 0, stream>>>(idI, partials);
    scan_partials_kernel<<<1, 1024, 0, stream>>>(partials);
    scan_write_kernel<<<NBLK, 256, 0, stream>>>(idI, partials, offs);
    fill2_kernel<<<dim3(HC, RELS, 2), 256, 0, stream>>>(src, dst, offs, slab16, edge_src);
    convw_kernel<<<(RELS * FIN * FHID + 255) / 256, 256, 0, stream>>>(W1, W2, W1t, W2t);

    // layer 1
    gemm1_kernel<<<GW, 256, 0, stream>>>(x, W1t, outnorm, h);
    gather1_kernel<<<NODES / 4, 256, 0, stream>>>(h, edge_src, offs, idI, innorm, b1, B);

    // layer 2
    gather2_kernel<<<dim3(NODES / 4, RELS), 256, 0, stream>>>(B, edge_src, offs, idI, outnorm, innorm, A2);
    out_kernel<<<GW, 256, 0, stream>>>(A2, W2t, b2, out);
}